// Round 5
// baseline (430.751 us; speedup 1.0000x reference)
//
#include <hip/hip_runtime.h>
#include <cstdint>

typedef __bf16 bf16;
typedef __bf16 bf16x8 __attribute__((ext_vector_type(8)));
typedef __bf16 bf16x4 __attribute__((ext_vector_type(4)));
typedef float  f32x4  __attribute__((ext_vector_type(4)));

#define MFMA_BF16(a, b, c) __builtin_amdgcn_mfma_f32_16x16x32_bf16(a, b, c, 0, 0, 0)

__device__ __forceinline__ bf16x8 cvt8(float4 lo, float4 hi) {
    bf16x8 o;
    o[0] = (bf16)lo.x; o[1] = (bf16)lo.y; o[2] = (bf16)lo.z; o[3] = (bf16)lo.w;
    o[4] = (bf16)hi.x; o[5] = (bf16)hi.y; o[6] = (bf16)hi.z; o[7] = (bf16)hi.w;
    return o;
}

// ---------------- QKV GEMM: C[4096,3072] = x @ w_qkv^T + b, scatter to Q/K/Vt ----------------
// fp32 inputs converted to bf16 during LDS staging.
__global__ __launch_bounds__(256) void gemm_qkv_kernel(
    const float* __restrict__ A,    // x [4096,1024] fp32
    const float* __restrict__ W,    // w_qkv [3072,1024] fp32
    const float* __restrict__ bias, // [3072]
    bf16* __restrict__ Qb, bf16* __restrict__ Kb, bf16* __restrict__ Vt)
{
    __shared__ bf16 sA[128 * 32];
    __shared__ bf16 sB[128 * 32];
    int tid = threadIdx.x, lane = tid & 63, wid = tid >> 6;
    int m0 = blockIdx.y * 128, n0 = blockIdx.x * 128;
    int row = tid >> 1;            // 0..127
    int cseg = (tid & 1) * 16;     // 0 or 16
    const float* Agf = A + (size_t)(m0 + row) * 1024 + cseg;
    const float* Wgf = W + (size_t)(n0 + row) * 1024 + cseg;
    int wm = (wid & 1) * 64, wn = (wid >> 1) * 64;
    int lcol = lane & 15, quad = lane >> 4;
    f32x4 acc[4][4] = {};
    for (int k0 = 0; k0 < 1024; k0 += 32) {
        float4 a0 = ((const float4*)(Agf + k0))[0];
        float4 a1 = ((const float4*)(Agf + k0))[1];
        float4 a2 = ((const float4*)(Agf + k0))[2];
        float4 a3 = ((const float4*)(Agf + k0))[3];
        float4 b0 = ((const float4*)(Wgf + k0))[0];
        float4 b1 = ((const float4*)(Wgf + k0))[1];
        float4 b2 = ((const float4*)(Wgf + k0))[2];
        float4 b3 = ((const float4*)(Wgf + k0))[3];
        __syncthreads();
        *(bf16x8*)&sA[row * 32 + cseg]     = cvt8(a0, a1);
        *(bf16x8*)&sA[row * 32 + cseg + 8] = cvt8(a2, a3);
        *(bf16x8*)&sB[row * 32 + cseg]     = cvt8(b0, b1);
        *(bf16x8*)&sB[row * 32 + cseg + 8] = cvt8(b2, b3);
        __syncthreads();
        bf16x8 af[4], bfr[4];
#pragma unroll
        for (int i = 0; i < 4; i++)
            af[i] = *(const bf16x8*)&sA[(wm + i * 16 + lcol) * 32 + quad * 8];
#pragma unroll
        for (int i = 0; i < 4; i++)
            bfr[i] = *(const bf16x8*)&sB[(wn + i * 16 + lcol) * 32 + quad * 8];
#pragma unroll
        for (int i = 0; i < 4; i++)
#pragma unroll
            for (int j = 0; j < 4; j++)
                acc[i][j] = MFMA_BF16(af[i], bfr[j], acc[i][j]);
    }
#pragma unroll
    for (int j = 0; j < 4; j++) {
        int n = n0 + wn + j * 16 + lcol;
        float bv = bias[n];
        int part = n >> 10, d = n & 1023, h = d >> 6, dd = d & 63;
#pragma unroll
        for (int i = 0; i < 4; i++) {
            int mb = m0 + wm + i * 16 + quad * 4;
            int b = mb >> 10, s = mb & 1023;
            if (part == 2) {
                bf16x4 v4;
#pragma unroll
                for (int r = 0; r < 4; r++) v4[r] = (bf16)(acc[i][j][r] + bv);
                *(bf16x4*)&Vt[(size_t)((b * 16 + h) * 64 + dd) * 1024 + s] = v4;
            } else {
                float scv = (part == 0) ? 0.125f : 1.0f;
                bf16* dst = (part == 0 ? Qb : Kb) + (size_t)((b * 16 + h) * 1024 + s) * 64 + dd;
#pragma unroll
                for (int r = 0; r < 4; r++) dst[(size_t)r * 64] = (bf16)((acc[i][j][r] + bv) * scv);
            }
        }
    }
}

// ---------------- out-proj GEMM: ao[4096,1024] = ctx(bf16) @ w_out^T + b (fp32 out) ----------------
__global__ __launch_bounds__(256) void gemm_out_kernel(
    const bf16* __restrict__ A,     // ctx [4096,1024] bf16
    const float* __restrict__ W,    // w_out [1024,1024] fp32
    const float* __restrict__ bias, // [1024]
    float* __restrict__ out)        // [4096,1024] fp32
{
    __shared__ bf16 sA[128 * 32];
    __shared__ bf16 sB[128 * 32];
    int tid = threadIdx.x, lane = tid & 63, wid = tid >> 6;
    int m0 = blockIdx.y * 128, n0 = blockIdx.x * 128;
    int srow = tid >> 2;
    int scol = (tid & 3) * 8;
    int wrow = tid >> 1;
    int wseg = (tid & 1) * 16;
    const bf16*  Ag  = A + (size_t)(m0 + srow) * 1024 + scol;
    const float* Wgf = W + (size_t)(n0 + wrow) * 1024 + wseg;
    int wm = (wid & 1) * 64, wn = (wid >> 1) * 64;
    int lcol = lane & 15, quad = lane >> 4;
    f32x4 acc[4][4] = {};
    for (int k0 = 0; k0 < 1024; k0 += 32) {
        bf16x8 a0 = *(const bf16x8*)(Ag + k0);
        bf16x8 a1 = *(const bf16x8*)(Ag + k0 + 64 * 1024);
        float4 b0 = ((const float4*)(Wgf + k0))[0];
        float4 b1 = ((const float4*)(Wgf + k0))[1];
        float4 b2 = ((const float4*)(Wgf + k0))[2];
        float4 b3 = ((const float4*)(Wgf + k0))[3];
        __syncthreads();
        *(bf16x8*)&sA[srow * 32 + scol] = a0;
        *(bf16x8*)&sA[(srow + 64) * 32 + scol] = a1;
        *(bf16x8*)&sB[wrow * 32 + wseg]     = cvt8(b0, b1);
        *(bf16x8*)&sB[wrow * 32 + wseg + 8] = cvt8(b2, b3);
        __syncthreads();
        bf16x8 af[4], bfr[4];
#pragma unroll
        for (int i = 0; i < 4; i++)
            af[i] = *(const bf16x8*)&sA[(wm + i * 16 + lcol) * 32 + quad * 8];
#pragma unroll
        for (int i = 0; i < 4; i++)
            bfr[i] = *(const bf16x8*)&sB[(wn + i * 16 + lcol) * 32 + quad * 8];
#pragma unroll
        for (int i = 0; i < 4; i++)
#pragma unroll
            for (int j = 0; j < 4; j++)
                acc[i][j] = MFMA_BF16(af[i], bfr[j], acc[i][j]);
    }
#pragma unroll
    for (int j = 0; j < 4; j++) {
        int n = n0 + wn + j * 16 + lcol;
        float bv = bias[n];
#pragma unroll
        for (int i = 0; i < 4; i++) {
            int m = m0 + wm + i * 16 + quad * 4;
#pragma unroll
            for (int r = 0; r < 4; r++) out[(size_t)(m + r) * 1024 + n] = acc[i][j][r] + bv;
        }
    }
}

// ---------------- fused attention ----------------
// grid 256: b = bx>>6, q0 = (bx&63)*16; all 16 heads per block.
// Writes ctx (bf16, ws) AND head-averaged attn weights (fp32, direct to d_out).
#define SD 1032  // bf16 score-row stride
__global__ __launch_bounds__(256) void attn_kernel(
    const bf16* __restrict__ Qb, const bf16* __restrict__ Kb, const bf16* __restrict__ Vt,
    bf16* __restrict__ ctx, float* __restrict__ aw)
{
    __shared__ bf16 sc[16 * SD];
    __shared__ float red[16][16];
    __shared__ float red2[16][16];
    __shared__ float rowinv[16];
    int tid = threadIdx.x, lane = tid & 63, wid = tid >> 6;
    int bx = blockIdx.x;
    int b = bx >> 6;
    int q0 = (bx & 63) * 16;
    int lcol = lane & 15, quad = lane >> 4;
    int r = tid & 15, cg = tid >> 4;
    float acc_w[64];
#pragma unroll
    for (int i = 0; i < 64; i++) acc_w[i] = 0.f;

    for (int h = 0; h < 16; h++) {
        size_t base = (size_t)(b * 16 + h) * 1024 * 64;
        const bf16* qp = Qb + base + (size_t)(q0 + lcol) * 64 + quad * 8;
        bf16x8 a0 = *(const bf16x8*)qp;
        bf16x8 a1 = *(const bf16x8*)(qp + 32);
        __syncthreads();  // prior head's consumers of sc are done
        const bf16* kp = Kb + base;
#pragma unroll
        for (int nt = 0; nt < 16; nt++) {
            int n0 = wid * 256 + nt * 16;
            const bf16* kr = kp + (size_t)(n0 + lcol) * 64 + quad * 8;
            bf16x8 b0 = *(const bf16x8*)kr;
            bf16x8 b1 = *(const bf16x8*)(kr + 32);
            f32x4 s = {};
            s = MFMA_BF16(a0, b0, s);
            s = MFMA_BF16(a1, b1, s);
#pragma unroll
            for (int rr = 0; rr < 4; rr++)
                sc[(quad * 4 + rr) * SD + n0 + lcol] = (bf16)s[rr];
        }
        __syncthreads();
        // softmax pass 1: row max
        float mx = -1e30f;
#pragma unroll
        for (int i8 = 0; i8 < 8; i8++) {
            bf16x8 v = *(const bf16x8*)&sc[r * SD + cg * 64 + i8 * 8];
#pragma unroll
            for (int j = 0; j < 8; j++) mx = fmaxf(mx, (float)v[j]);
        }
        red[r][cg] = mx;
        __syncthreads();
#pragma unroll
        for (int i = 0; i < 16; i++) mx = fmaxf(mx, red[r][i]);
        // pass 2: e = exp(s - mx) stored bf16, partial row sums
        float l = 0.f;
#pragma unroll
        for (int i8 = 0; i8 < 8; i8++) {
            bf16x8 v = *(const bf16x8*)&sc[r * SD + cg * 64 + i8 * 8];
            bf16x8 e;
#pragma unroll
            for (int j = 0; j < 8; j++) { float ev = __expf((float)v[j] - mx); l += ev; e[j] = (bf16)ev; }
            *(bf16x8*)&sc[r * SD + cg * 64 + i8 * 8] = e;
        }
        red2[r][cg] = l;
        __syncthreads();
        l = 0.f;
#pragma unroll
        for (int i = 0; i < 16; i++) l += red2[r][i];
        float inv_l = 1.f / l;
        if (cg == 0) rowinv[r] = inv_l;
        // pass 3: accumulate head-mean partial
#pragma unroll
        for (int i8 = 0; i8 < 8; i8++) {
            bf16x8 e = *(const bf16x8*)&sc[r * SD + cg * 64 + i8 * 8];
#pragma unroll
            for (int j = 0; j < 8; j++) acc_w[i8 * 8 + j] += (float)e[j] * inv_l;
        }
        __syncthreads();  // rowinv visible; e-writes done before PV reads
        // PV: wave handles d in [wid*16, wid*16+16)
        const bf16* vp = Vt + (size_t)(b * 16 + h) * 64 * 1024 + (size_t)(wid * 16 + lcol) * 1024 + quad * 8;
        f32x4 o = {};
#pragma unroll
        for (int kt = 0; kt < 32; kt++) {
            bf16x8 pa = *(const bf16x8*)&sc[lcol * SD + kt * 32 + quad * 8];
            bf16x8 vb = *(const bf16x8*)(vp + (size_t)kt * 32);
            o = MFMA_BF16(pa, vb, o);
        }
#pragma unroll
        for (int rr = 0; rr < 4; rr++) {
            int m = quad * 4 + rr;
            ctx[(size_t)(b * 1024 + q0 + m) * 1024 + h * 64 + wid * 16 + lcol] =
                (bf16)(o[rr] * rowinv[m]);
        }
    }
    // head-averaged weights: thread (r,cg) owns row q0+r, cols cg*64..+63. fp32 direct store.
    float* outp = aw + (size_t)(b * 1024 + q0 + r) * 1024 + cg * 64;
#pragma unroll
    for (int i8 = 0; i8 < 8; i8++) {
        float4 lo = {acc_w[i8 * 8 + 0] * 0.0625f, acc_w[i8 * 8 + 1] * 0.0625f,
                     acc_w[i8 * 8 + 2] * 0.0625f, acc_w[i8 * 8 + 3] * 0.0625f};
        float4 hi = {acc_w[i8 * 8 + 4] * 0.0625f, acc_w[i8 * 8 + 5] * 0.0625f,
                     acc_w[i8 * 8 + 6] * 0.0625f, acc_w[i8 * 8 + 7] * 0.0625f};
        *(float4*)(outp + i8 * 8)     = lo;
        *(float4*)(outp + i8 * 8 + 4) = hi;
    }
}

// ---------------- residual + LayerNorm (fp32 output) ----------------
__global__ __launch_bounds__(256) void ln_kernel(
    const float* __restrict__ x, const float* __restrict__ ao,
    const float* __restrict__ w, const float* __restrict__ bsh,
    float* __restrict__ y)
{
    int row = blockIdx.x, tid = threadIdx.x;
    float4 xv = ((const float4*)(x + (size_t)row * 1024))[tid];
    float4 av = ((const float4*)(ao + (size_t)row * 1024))[tid];
    float4 v = {xv.x + av.x, xv.y + av.y, xv.z + av.z, xv.w + av.w};
    float s = v.x + v.y + v.z + v.w;
    float ss = v.x * v.x + v.y * v.y + v.z * v.z + v.w * v.w;
#pragma unroll
    for (int off = 32; off; off >>= 1) { s += __shfl_down(s, off); ss += __shfl_down(ss, off); }
    __shared__ float rs[4], rss[4];
    int lane = tid & 63, wid = tid >> 6;
    if (lane == 0) { rs[wid] = s; rss[wid] = ss; }
    __syncthreads();
    s = rs[0] + rs[1] + rs[2] + rs[3];
    ss = rss[0] + rss[1] + rss[2] + rss[3];
    float mean = s * (1.f / 1024.f);
    float var = ss * (1.f / 1024.f) - mean * mean;
    float inv = rsqrtf(var + 1e-5f);
    float4 wv = ((const float4*)w)[tid];
    float4 bv = ((const float4*)bsh)[tid];
    float4 o;
    o.x = (v.x - mean) * inv * wv.x + bv.x;
    o.y = (v.y - mean) * inv * wv.y + bv.y;
    o.z = (v.z - mean) * inv * wv.z + bv.z;
    o.w = (v.w - mean) * inv * wv.w + bv.w;
    ((float4*)y)[row * 256 + tid] = o;
}

extern "C" void kernel_launch(void* const* d_in, const int* in_sizes, int n_in,
                              void* d_out, int out_size, void* d_ws, size_t ws_size,
                              hipStream_t stream) {
    const float* x     = (const float*)d_in[0];
    const float* w_qkv = (const float*)d_in[1];
    const float* b_qkv = (const float*)d_in[2];
    const float* w_out = (const float*)d_in[3];
    const float* b_out = (const float*)d_in[4];
    const float* ln_w  = (const float*)d_in[5];
    const float* ln_b  = (const float*)d_in[6];

    char* ws = (char*)d_ws;
    // Peak 32 MiB: [0,8M) Qb | [8,16M) Kb | [16,24M) Vt | [24,32M) ctx
    // ao (fp32, 16 MB) overlays [0,16M) after attention (Qb/Kb dead).
    bf16*  Qb  = (bf16*)(ws);
    bf16*  Kb  = (bf16*)(ws + (8ull  << 20));
    bf16*  Vt  = (bf16*)(ws + (16ull << 20));
    bf16*  ctx = (bf16*)(ws + (24ull << 20));
    float* ao  = (float*)(ws);

    // Reference outputs are float32 -> d_out is float* (y[4M] then attn_weights[4M]).
    float* y_out  = (float*)d_out;
    float* aw_out = y_out + 4ull * 1024 * 1024;

    gemm_qkv_kernel<<<dim3(24, 32), 256, 0, stream>>>(x, w_qkv, b_qkv, Qb, Kb, Vt);
    attn_kernel<<<256, 256, 0, stream>>>(Qb, Kb, Vt, ctx, aw_out);
    gemm_out_kernel<<<dim3(8, 32), 256, 0, stream>>>(ctx, w_out, b_out, ao);
    ln_kernel<<<4096, 256, 0, stream>>>(x, ao, ln_w, ln_b, y_out);
}

// Round 6
// 356.086 us; speedup vs baseline: 1.2097x; 1.2097x over previous
//
#include <hip/hip_runtime.h>
#include <cstdint>

typedef __bf16 bf16;
typedef __bf16 bf16x8 __attribute__((ext_vector_type(8)));
typedef __bf16 bf16x4 __attribute__((ext_vector_type(4)));
typedef float  f32x4  __attribute__((ext_vector_type(4)));

#define MFMA_BF16(a, b, c) __builtin_amdgcn_mfma_f32_16x16x32_bf16(a, b, c, 0, 0, 0)

__device__ __forceinline__ bf16x8 cvt8(float4 lo, float4 hi) {
    bf16x8 o;
    o[0] = (bf16)lo.x; o[1] = (bf16)lo.y; o[2] = (bf16)lo.z; o[3] = (bf16)lo.w;
    o[4] = (bf16)hi.x; o[5] = (bf16)hi.y; o[6] = (bf16)hi.z; o[7] = (bf16)hi.w;
    return o;
}

// ---------------- QKV GEMM: C[4096,3072] = x @ w_qkv^T + b, scatter to Q/K/Vt ----------------
__global__ __launch_bounds__(256) void gemm_qkv_kernel(
    const float* __restrict__ A,    // x [4096,1024] fp32
    const float* __restrict__ W,    // w_qkv [3072,1024] fp32
    const float* __restrict__ bias, // [3072]
    bf16* __restrict__ Qb, bf16* __restrict__ Kb, bf16* __restrict__ Vt)
{
    __shared__ bf16 sA[128 * 32];
    __shared__ bf16 sB[128 * 32];
    int tid = threadIdx.x, lane = tid & 63, wid = tid >> 6;
    int m0 = blockIdx.y * 128, n0 = blockIdx.x * 128;
    int row = tid >> 1;            // 0..127
    int cseg = (tid & 1) * 16;     // 0 or 16
    const float* Agf = A + (size_t)(m0 + row) * 1024 + cseg;
    const float* Wgf = W + (size_t)(n0 + row) * 1024 + cseg;
    int wm = (wid & 1) * 64, wn = (wid >> 1) * 64;
    int lcol = lane & 15, quad = lane >> 4;
    f32x4 acc[4][4] = {};
    for (int k0 = 0; k0 < 1024; k0 += 32) {
        float4 a0 = ((const float4*)(Agf + k0))[0];
        float4 a1 = ((const float4*)(Agf + k0))[1];
        float4 a2 = ((const float4*)(Agf + k0))[2];
        float4 a3 = ((const float4*)(Agf + k0))[3];
        float4 b0 = ((const float4*)(Wgf + k0))[0];
        float4 b1 = ((const float4*)(Wgf + k0))[1];
        float4 b2 = ((const float4*)(Wgf + k0))[2];
        float4 b3 = ((const float4*)(Wgf + k0))[3];
        __syncthreads();
        *(bf16x8*)&sA[row * 32 + cseg]     = cvt8(a0, a1);
        *(bf16x8*)&sA[row * 32 + cseg + 8] = cvt8(a2, a3);
        *(bf16x8*)&sB[row * 32 + cseg]     = cvt8(b0, b1);
        *(bf16x8*)&sB[row * 32 + cseg + 8] = cvt8(b2, b3);
        __syncthreads();
        bf16x8 af[4], bfr[4];
#pragma unroll
        for (int i = 0; i < 4; i++)
            af[i] = *(const bf16x8*)&sA[(wm + i * 16 + lcol) * 32 + quad * 8];
#pragma unroll
        for (int i = 0; i < 4; i++)
            bfr[i] = *(const bf16x8*)&sB[(wn + i * 16 + lcol) * 32 + quad * 8];
#pragma unroll
        for (int i = 0; i < 4; i++)
#pragma unroll
            for (int j = 0; j < 4; j++)
                acc[i][j] = MFMA_BF16(af[i], bfr[j], acc[i][j]);
    }
#pragma unroll
    for (int j = 0; j < 4; j++) {
        int n = n0 + wn + j * 16 + lcol;
        float bv = bias[n];
        int part = n >> 10, d = n & 1023, h = d >> 6, dd = d & 63;
#pragma unroll
        for (int i = 0; i < 4; i++) {
            int mb = m0 + wm + i * 16 + quad * 4;
            int b = mb >> 10, s = mb & 1023;
            if (part == 2) {
                bf16x4 v4;
#pragma unroll
                for (int r = 0; r < 4; r++) v4[r] = (bf16)(acc[i][j][r] + bv);
                *(bf16x4*)&Vt[(size_t)((b * 16 + h) * 64 + dd) * 1024 + s] = v4;
            } else {
                float scv = (part == 0) ? 0.125f : 1.0f;
                bf16* dst = (part == 0 ? Qb : Kb) + (size_t)((b * 16 + h) * 1024 + s) * 64 + dd;
#pragma unroll
                for (int r = 0; r < 4; r++) dst[(size_t)r * 64] = (bf16)((acc[i][j][r] + bv) * scv);
            }
        }
    }
}

// ---------------- out-proj GEMM: ao[4096,1024] = ctx(bf16) @ w_out^T + b (fp32 out) ----------------
__global__ __launch_bounds__(256) void gemm_out_kernel(
    const bf16* __restrict__ A,     // ctx [4096,1024] bf16
    const float* __restrict__ W,    // w_out [1024,1024] fp32
    const float* __restrict__ bias, // [1024]
    float* __restrict__ out)        // [4096,1024] fp32
{
    __shared__ bf16 sA[128 * 32];
    __shared__ bf16 sB[128 * 32];
    int tid = threadIdx.x, lane = tid & 63, wid = tid >> 6;
    int m0 = blockIdx.y * 128, n0 = blockIdx.x * 128;
    int srow = tid >> 2;
    int scol = (tid & 3) * 8;
    int wrow = tid >> 1;
    int wseg = (tid & 1) * 16;
    const bf16*  Ag  = A + (size_t)(m0 + srow) * 1024 + scol;
    const float* Wgf = W + (size_t)(n0 + wrow) * 1024 + wseg;
    int wm = (wid & 1) * 64, wn = (wid >> 1) * 64;
    int lcol = lane & 15, quad = lane >> 4;
    f32x4 acc[4][4] = {};
    for (int k0 = 0; k0 < 1024; k0 += 32) {
        bf16x8 a0 = *(const bf16x8*)(Ag + k0);
        bf16x8 a1 = *(const bf16x8*)(Ag + k0 + 64 * 1024);
        float4 b0 = ((const float4*)(Wgf + k0))[0];
        float4 b1 = ((const float4*)(Wgf + k0))[1];
        float4 b2 = ((const float4*)(Wgf + k0))[2];
        float4 b3 = ((const float4*)(Wgf + k0))[3];
        __syncthreads();
        *(bf16x8*)&sA[srow * 32 + scol] = a0;
        *(bf16x8*)&sA[(srow + 64) * 32 + scol] = a1;
        *(bf16x8*)&sB[wrow * 32 + wseg]     = cvt8(b0, b1);
        *(bf16x8*)&sB[wrow * 32 + wseg + 8] = cvt8(b2, b3);
        __syncthreads();
        bf16x8 af[4], bfr[4];
#pragma unroll
        for (int i = 0; i < 4; i++)
            af[i] = *(const bf16x8*)&sA[(wm + i * 16 + lcol) * 32 + quad * 8];
#pragma unroll
        for (int i = 0; i < 4; i++)
            bfr[i] = *(const bf16x8*)&sB[(wn + i * 16 + lcol) * 32 + quad * 8];
#pragma unroll
        for (int i = 0; i < 4; i++)
#pragma unroll
            for (int j = 0; j < 4; j++)
                acc[i][j] = MFMA_BF16(af[i], bfr[j], acc[i][j]);
    }
#pragma unroll
    for (int j = 0; j < 4; j++) {
        int n = n0 + wn + j * 16 + lcol;
        float bv = bias[n];
#pragma unroll
        for (int i = 0; i < 4; i++) {
            int m = m0 + wm + i * 16 + quad * 4;
#pragma unroll
            for (int r = 0; r < 4; r++) out[(size_t)(m + r) * 1024 + n] = acc[i][j][r] + bv;
        }
    }
}

// ---------------- fused attention ----------------
// grid 1024: b = bx>>8, q0 = ((bx>>2)&63)*16, g = bx&3 (heads g*4..g*4+3).
// Writes ctx (bf16) + bf16 partial head-sums pw[g] (already /16).
#define SD 1032  // bf16 score-row stride
__global__ __launch_bounds__(256) void attn_kernel(
    const bf16* __restrict__ Qb, const bf16* __restrict__ Kb, const bf16* __restrict__ Vt,
    bf16* __restrict__ ctx, bf16* __restrict__ pw)
{
    __shared__ bf16 sc[16 * SD];
    __shared__ float red[16][16];
    __shared__ float red2[16][16];
    __shared__ float rowinv[16];
    int tid = threadIdx.x, lane = tid & 63, wid = tid >> 6;
    int bx = blockIdx.x;
    int g = bx & 3;
    int q0 = ((bx >> 2) & 63) * 16;
    int b = bx >> 8;
    int lcol = lane & 15, quad = lane >> 4;
    int r = tid & 15, cg = tid >> 4;
    float acc_w[64];
#pragma unroll
    for (int i = 0; i < 64; i++) acc_w[i] = 0.f;

    for (int hh = 0; hh < 4; hh++) {
        int h = g * 4 + hh;
        size_t base = (size_t)(b * 16 + h) * 1024 * 64;
        const bf16* qp = Qb + base + (size_t)(q0 + lcol) * 64 + quad * 8;
        bf16x8 a0 = *(const bf16x8*)qp;
        bf16x8 a1 = *(const bf16x8*)(qp + 32);
        __syncthreads();  // prior head's consumers of sc are done
        const bf16* kp = Kb + base;
#pragma unroll
        for (int nt = 0; nt < 16; nt++) {
            int n0 = wid * 256 + nt * 16;
            const bf16* kr = kp + (size_t)(n0 + lcol) * 64 + quad * 8;
            bf16x8 b0 = *(const bf16x8*)kr;
            bf16x8 b1 = *(const bf16x8*)(kr + 32);
            f32x4 s = {};
            s = MFMA_BF16(a0, b0, s);
            s = MFMA_BF16(a1, b1, s);
#pragma unroll
            for (int rr = 0; rr < 4; rr++)
                sc[(quad * 4 + rr) * SD + n0 + lcol] = (bf16)s[rr];
        }
        __syncthreads();
        // softmax pass 1: row max
        float mx = -1e30f;
#pragma unroll
        for (int i8 = 0; i8 < 8; i8++) {
            bf16x8 v = *(const bf16x8*)&sc[r * SD + cg * 64 + i8 * 8];
#pragma unroll
            for (int j = 0; j < 8; j++) mx = fmaxf(mx, (float)v[j]);
        }
        red[r][cg] = mx;
        __syncthreads();
#pragma unroll
        for (int i = 0; i < 16; i++) mx = fmaxf(mx, red[r][i]);
        // pass 2: e = exp(s - mx) stored bf16, partial row sums
        float l = 0.f;
#pragma unroll
        for (int i8 = 0; i8 < 8; i8++) {
            bf16x8 v = *(const bf16x8*)&sc[r * SD + cg * 64 + i8 * 8];
            bf16x8 e;
#pragma unroll
            for (int j = 0; j < 8; j++) { float ev = __expf((float)v[j] - mx); l += ev; e[j] = (bf16)ev; }
            *(bf16x8*)&sc[r * SD + cg * 64 + i8 * 8] = e;
        }
        red2[r][cg] = l;
        __syncthreads();
        l = 0.f;
#pragma unroll
        for (int i = 0; i < 16; i++) l += red2[r][i];
        float inv_l = 1.f / l;
        if (cg == 0) rowinv[r] = inv_l;
        // pass 3: accumulate head-mean partial
#pragma unroll
        for (int i8 = 0; i8 < 8; i8++) {
            bf16x8 e = *(const bf16x8*)&sc[r * SD + cg * 64 + i8 * 8];
#pragma unroll
            for (int j = 0; j < 8; j++) acc_w[i8 * 8 + j] += (float)e[j] * inv_l;
        }
        __syncthreads();  // rowinv visible; e-writes done before PV reads
        // PV: wave handles d in [wid*16, wid*16+16)
        const bf16* vp = Vt + (size_t)(b * 16 + h) * 64 * 1024 + (size_t)(wid * 16 + lcol) * 1024 + quad * 8;
        f32x4 o = {};
#pragma unroll
        for (int kt = 0; kt < 32; kt++) {
            bf16x8 pa = *(const bf16x8*)&sc[lcol * SD + kt * 32 + quad * 8];
            bf16x8 vb = *(const bf16x8*)(vp + (size_t)kt * 32);
            o = MFMA_BF16(pa, vb, o);
        }
#pragma unroll
        for (int rr = 0; rr < 4; rr++) {
            int m = quad * 4 + rr;
            ctx[(size_t)(b * 1024 + q0 + m) * 1024 + h * 64 + wid * 16 + lcol] =
                (bf16)(o[rr] * rowinv[m]);
        }
    }
    // bf16 partial head-sum (already /16): thread (r,cg) owns row q0+r, cols cg*64..+63
    bf16* outp = pw + ((size_t)(g * 4 + b) * 1024 + q0 + r) * 1024 + cg * 64;
#pragma unroll
    for (int i8 = 0; i8 < 8; i8++) {
        bf16x8 v;
#pragma unroll
        for (int j = 0; j < 8; j++) v[j] = (bf16)(acc_w[i8 * 8 + j] * 0.0625f);
        *(bf16x8*)(outp + i8 * 8) = v;
    }
}

// ---------------- combine 4 head-group partials -> fp32 aw ----------------
__global__ __launch_bounds__(256) void combine_kernel(const bf16* __restrict__ pw, float* __restrict__ aw) {
    const size_t NP = 4ull * 1024 * 1024;  // elems per partial
    size_t i = ((size_t)blockIdx.x * 256 + threadIdx.x) * 8;
    bf16x8 p0 = *(const bf16x8*)(pw + i);
    bf16x8 p1 = *(const bf16x8*)(pw + NP + i);
    bf16x8 p2 = *(const bf16x8*)(pw + 2 * NP + i);
    bf16x8 p3 = *(const bf16x8*)(pw + 3 * NP + i);
    float4 lo, hi;
    lo.x = (float)p0[0] + (float)p1[0] + (float)p2[0] + (float)p3[0];
    lo.y = (float)p0[1] + (float)p1[1] + (float)p2[1] + (float)p3[1];
    lo.z = (float)p0[2] + (float)p1[2] + (float)p2[2] + (float)p3[2];
    lo.w = (float)p0[3] + (float)p1[3] + (float)p2[3] + (float)p3[3];
    hi.x = (float)p0[4] + (float)p1[4] + (float)p2[4] + (float)p3[4];
    hi.y = (float)p0[5] + (float)p1[5] + (float)p2[5] + (float)p3[5];
    hi.z = (float)p0[6] + (float)p1[6] + (float)p2[6] + (float)p3[6];
    hi.w = (float)p0[7] + (float)p1[7] + (float)p2[7] + (float)p3[7];
    *(float4*)(aw + i)     = lo;
    *(float4*)(aw + i + 4) = hi;
}

// ---------------- residual + LayerNorm (fp32 output) ----------------
__global__ __launch_bounds__(256) void ln_kernel(
    const float* __restrict__ x, const float* __restrict__ ao,
    const float* __restrict__ w, const float* __restrict__ bsh,
    float* __restrict__ y)
{
    int row = blockIdx.x, tid = threadIdx.x;
    float4 xv = ((const float4*)(x + (size_t)row * 1024))[tid];
    float4 av = ((const float4*)(ao + (size_t)row * 1024))[tid];
    float4 v = {xv.x + av.x, xv.y + av.y, xv.z + av.z, xv.w + av.w};
    float s = v.x + v.y + v.z + v.w;
    float ss = v.x * v.x + v.y * v.y + v.z * v.z + v.w * v.w;
#pragma unroll
    for (int off = 32; off; off >>= 1) { s += __shfl_down(s, off); ss += __shfl_down(ss, off); }
    __shared__ float rs[4], rss[4];
    int lane = tid & 63, wid = tid >> 6;
    if (lane == 0) { rs[wid] = s; rss[wid] = ss; }
    __syncthreads();
    s = rs[0] + rs[1] + rs[2] + rs[3];
    ss = rss[0] + rss[1] + rss[2] + rss[3];
    float mean = s * (1.f / 1024.f);
    float var = ss * (1.f / 1024.f) - mean * mean;
    float inv = rsqrtf(var + 1e-5f);
    float4 wv = ((const float4*)w)[tid];
    float4 bv = ((const float4*)bsh)[tid];
    float4 o;
    o.x = (v.x - mean) * inv * wv.x + bv.x;
    o.y = (v.y - mean) * inv * wv.y + bv.y;
    o.z = (v.z - mean) * inv * wv.z + bv.z;
    o.w = (v.w - mean) * inv * wv.w + bv.w;
    ((float4*)y)[row * 256 + tid] = o;
}

extern "C" void kernel_launch(void* const* d_in, const int* in_sizes, int n_in,
                              void* d_out, int out_size, void* d_ws, size_t ws_size,
                              hipStream_t stream) {
    const float* x     = (const float*)d_in[0];
    const float* w_qkv = (const float*)d_in[1];
    const float* b_qkv = (const float*)d_in[2];
    const float* w_out = (const float*)d_in[3];
    const float* b_out = (const float*)d_in[4];
    const float* ln_w  = (const float*)d_in[5];
    const float* ln_b  = (const float*)d_in[6];

    char* ws = (char*)d_ws;
    // Peak 64 MiB: [0,8M) Qb | [8,16M) Kb | [16,24M) Vt | [24,32M) ctx | [32,64M) pw (4 bf16 partials)
    // ao (fp32, 16 MB) overlays [0,16M) after attention (Qb/Kb dead).
    bf16*  Qb  = (bf16*)(ws);
    bf16*  Kb  = (bf16*)(ws + (8ull  << 20));
    bf16*  Vt  = (bf16*)(ws + (16ull << 20));
    bf16*  ctx = (bf16*)(ws + (24ull << 20));
    bf16*  pw  = (bf16*)(ws + (32ull << 20));
    float* ao  = (float*)(ws);

    float* y_out  = (float*)d_out;
    float* aw_out = y_out + 4ull * 1024 * 1024;

    gemm_qkv_kernel<<<dim3(24, 32), 256, 0, stream>>>(x, w_qkv, b_qkv, Qb, Kb, Vt);
    attn_kernel<<<1024, 256, 0, stream>>>(Qb, Kb, Vt, ctx, pw);
    gemm_out_kernel<<<dim3(8, 32), 256, 0, stream>>>(ctx, w_out, b_out, ao);
    combine_kernel<<<2048, 256, 0, stream>>>(pw, aw_out);
    ln_kernel<<<4096, 256, 0, stream>>>(x, ao, ln_w, ln_b, y_out);
}